// Round 1
// 4334.318 us; speedup vs baseline: 1.4124x; 1.4124x over previous
//
#include <hip/hip_runtime.h>
#include <hip/hip_bf16.h>

#define DEVINL __device__ __forceinline__

constexpr int B_   = 4;
constexpr int T_   = 2048;
constexpr int C_   = 1024;
constexpr int NTOK = B_ * T_;      // 8192
constexpr int HD   = 256;          // C_/4

typedef unsigned short u16;
typedef __attribute__((ext_vector_type(8))) short  frag_ab;  // 8 bf16 (4 VGPRs)
typedef __attribute__((ext_vector_type(4))) float  frag_cd;  // 4 fp32
typedef __attribute__((ext_vector_type(8))) u16    u16x8;

DEVINL float bf2f(u16 u) {
    unsigned int x = ((unsigned int)u) << 16;
    return __uint_as_float(x);
}
DEVINL u16 f2bf(float f) {
    unsigned int x = __float_as_uint(f);
    unsigned int r = (x + 0x7fffu + ((x >> 16) & 1u)) >> 16;
    return (u16)r;
}
// f == bf2f(h) + bf2f(l) + O(2^-17 |f|); the residual subtraction is exact
// (Sterbenz: h within factor 2 of f), so dropped error is only lo's rounding.
DEVINL void split2(float f, u16& h, u16& l) {
    h = f2bf(f);
    l = f2bf(f - bf2f(h));
}
DEVINL float wave_reduce(float v) {
    #pragma unroll
    for (int off = 32; off > 0; off >>= 1) v += __shfl_down(v, off, 64);
    return v;
}
DEVINL void gl_lds16(const void* g, void* l) {
    __builtin_amdgcn_global_load_lds(
        (const __attribute__((address_space(1))) unsigned int*)g,
        (__attribute__((address_space(3))) unsigned int*)l, 16, 0, 0);
}

// ---------------------------------------------------------------------------
// dtype auto-detect (flag: 1 = bf16 inputs, 0 = f32 inputs)
// ---------------------------------------------------------------------------
__global__ __launch_bounds__(256) void detect_k(const u16* __restrict__ w,
                                                int* __restrict__ flag)
{
    int tid = threadIdx.x;
    int cnt = 0;
    for (int i = tid; i < 4096; i += 256) {
        u16 u = w[2 * i];
        int e = (u >> 7) & 0xFF;
        if (u == 0 || (e >= 96 && e <= 134)) cnt++;
    }
    __shared__ int sh[256];
    sh[tid] = cnt; __syncthreads();
    for (int s = 128; s > 0; s >>= 1) {
        if (tid < s) sh[tid] += sh[tid + s];
        __syncthreads();
    }
    if (tid == 0) *flag = (sh[0] > 2048) ? 1 : 0;
}

__global__ __launch_bounds__(256) void conv_k(const void* __restrict__ src,
                                              float* __restrict__ dst, int n,
                                              const int* __restrict__ flag)
{
    int i = blockIdx.x * 256 + threadIdx.x;
    if (i >= n) return;
    if (*flag) dst[i] = bf2f(((const u16*)src)[i]);
    else       dst[i] = ((const float*)src)[i];
}

__global__ __launch_bounds__(256) void sumsq_k(const float* __restrict__ X,
                                               float* __restrict__ sumsq)
{
    int i = blockIdx.x * 256 + threadIdx.x;
    float f = X[i];
    float p = wave_reduce(f * f);
    __shared__ float r[4];
    int lane = threadIdx.x & 63, w = threadIdx.x >> 6;
    if (lane == 0) r[w] = p;
    __syncthreads();
    if (threadIdx.x == 0) atomicAdd(sumsq, r[0] + r[1] + r[2] + r[3]);
}

__global__ __launch_bounds__(256) void scale_k(float* __restrict__ X,
                                               const float* __restrict__ sumsq)
{
    int i = blockIdx.x * 256 + threadIdx.x;
    float F = sqrtf(*sumsq);
    float s = 16.0f / (1.1f * F);   // Gaussian: sigma_max ~= F/16; 10% margin
    X[i] *= s;
}

// ---------------------------------------------------------------------------
// f32 tiled GEMMs — EXACT round-2 kernels (bit-proven NS path, kept as-is)
// ---------------------------------------------------------------------------
__global__ __launch_bounds__(256) void gemm_ab_f32(
    const float* __restrict__ A, const float* __restrict__ Bm,
    const float* __restrict__ D, float* __restrict__ C,
    int M, int N, int K, float alpha, float beta)
{
    __shared__ float As[16][68];
    __shared__ float Bs[16][68];
    const int bm = blockIdx.y * 64, bn = blockIdx.x * 64;
    const int tid = threadIdx.x;
    const int tx = tid & 15, ty = tid >> 4;
    const int am = tid >> 2, akq = (tid & 3) << 2;
    const int bk = tid >> 4, bnq = (tid & 15) << 2;
    float acc[4][4] = {};
    for (int k0 = 0; k0 < K; k0 += 16) {
        float4 av = *(const float4*)(A + (size_t)(bm + am) * K + k0 + akq);
        As[akq + 0][am] = av.x; As[akq + 1][am] = av.y;
        As[akq + 2][am] = av.z; As[akq + 3][am] = av.w;
        *(float4*)&Bs[bk][bnq] = *(const float4*)(Bm + (size_t)(k0 + bk) * N + bn + bnq);
        __syncthreads();
        #pragma unroll
        for (int k = 0; k < 16; ++k) {
            float a4[4], b4[4];
            *(float4*)a4 = *(const float4*)&As[k][ty << 2];
            *(float4*)b4 = *(const float4*)&Bs[k][tx << 2];
            #pragma unroll
            for (int i = 0; i < 4; ++i)
                #pragma unroll
                for (int j = 0; j < 4; ++j) acc[i][j] += a4[i] * b4[j];
        }
        __syncthreads();
    }
    #pragma unroll
    for (int i = 0; i < 4; ++i) {
        size_t row = (size_t)(bm + (ty << 2) + i);
        #pragma unroll
        for (int j = 0; j < 4; ++j) {
            size_t idx = row * N + bn + (tx << 2) + j;
            float v = beta * acc[i][j];
            if (D) v += alpha * D[idx];
            C[idx] = v;
        }
    }
}

__global__ __launch_bounds__(256) void gemm_atb_f32(
    const float* __restrict__ A, const float* __restrict__ Bm,
    float* __restrict__ C, int M, int N, int K)
{
    __shared__ float As[16][68];
    __shared__ float Bs[16][68];
    const int bm = blockIdx.y * 64, bn = blockIdx.x * 64;
    const int tid = threadIdx.x;
    const int tx = tid & 15, ty = tid >> 4;
    const int bk = tid >> 4, bq = (tid & 15) << 2;
    float acc[4][4] = {};
    for (int k0 = 0; k0 < K; k0 += 16) {
        *(float4*)&As[bk][bq] = *(const float4*)(A + (size_t)(k0 + bk) * M + bm + bq);
        *(float4*)&Bs[bk][bq] = *(const float4*)(Bm + (size_t)(k0 + bk) * N + bn + bq);
        __syncthreads();
        #pragma unroll
        for (int k = 0; k < 16; ++k) {
            float a4[4], b4[4];
            *(float4*)a4 = *(const float4*)&As[k][ty << 2];
            *(float4*)b4 = *(const float4*)&Bs[k][tx << 2];
            #pragma unroll
            for (int i = 0; i < 4; ++i)
                #pragma unroll
                for (int j = 0; j < 4; ++j) acc[i][j] += a4[i] * b4[j];
        }
        __syncthreads();
    }
    #pragma unroll
    for (int i = 0; i < 4; ++i) {
        size_t row = (size_t)(bm + (ty << 2) + i);
        #pragma unroll
        for (int j = 0; j < 4; ++j)
            C[row * N + bn + (tx << 2) + j] = acc[i][j];
    }
}

// ---------------------------------------------------------------------------
// MFMA bf16 GEMM (plain): C[m,n] = sum_k A[m,k] * B[n,k]
// Output-0 path only (v, final projection) — UNCHANGED proven kernel.
// ---------------------------------------------------------------------------
__global__ __launch_bounds__(256) void gemm_mfma(
    const void* __restrict__ Asrc, const float* __restrict__ Vf, int amode,
    const void* __restrict__ Bsrc, int bmode,
    void* __restrict__ Cdst, int cmode,
    const int* __restrict__ flag, int M, int N, int K)
{
    __shared__ u16 As[128 * 32];
    __shared__ u16 Bs[128 * 32];
    const int fl  = *flag;
    const int abf = (amode == 2) ? fl : amode;
    const int bbf = (bmode == 2) ? fl : bmode;
    const int cbf = (cmode == 1) ? fl : 0;

    const int bm = blockIdx.y * 128, bn = blockIdx.x * 128;
    const int tid = threadIdx.x;
    const int l = tid & 63, w = tid >> 6;
    const int mbase = (w & 1) * 64, nbase = (w >> 1) * 64;
    const int lrow = l & 15;
    const int kq = (l >> 4) << 3;

    const u16*   Ab = (const u16*)Asrc;
    const float* Af = (const float*)Asrc;
    const u16*   Bb = (const u16*)Bsrc;
    const float* Bf = (const float*)Bsrc;

    frag_cd acc[4][4];
    #pragma unroll
    for (int i = 0; i < 4; ++i)
        #pragma unroll
        for (int j = 0; j < 4; ++j)
            #pragma unroll
            for (int r = 0; r < 4; ++r) acc[i][j][r] = 0.0f;

    for (int k0 = 0; k0 < K; k0 += 32) {
        #pragma unroll
        for (int half = 0; half < 2; ++half) {
            const int c   = tid + half * 256;
            const int row = c >> 2;
            const int ko  = (c & 3) << 3;
            u16* lA = &As[c << 3];
            if (abf) {
                gl_lds16(Ab + (size_t)(bm + row) * K + k0 + ko, lA);
            } else {
                const float* src = Af + (size_t)(bm + row) * K + k0 + ko;
                float4 f0 = *(const float4*)(src);
                float4 f1 = *(const float4*)(src + 4);
                if (Vf) {
                    const float* vs = Vf + (size_t)(bm + row) * K + k0 + ko;
                    float4 v0 = *(const float4*)(vs);
                    float4 v1 = *(const float4*)(vs + 4);
                    f0.x *= v0.x; f0.y *= v0.y; f0.z *= v0.z; f0.w *= v0.w;
                    f1.x *= v1.x; f1.y *= v1.y; f1.z *= v1.z; f1.w *= v1.w;
                }
                u16x8 p;
                p[0] = f2bf(f0.x); p[1] = f2bf(f0.y); p[2] = f2bf(f0.z); p[3] = f2bf(f0.w);
                p[4] = f2bf(f1.x); p[5] = f2bf(f1.y); p[6] = f2bf(f1.z); p[7] = f2bf(f1.w);
                *(u16x8*)lA = p;
            }
            u16* lB = &Bs[c << 3];
            if (bbf) {
                gl_lds16(Bb + (size_t)(bn + row) * K + k0 + ko, lB);
            } else {
                const float* src = Bf + (size_t)(bn + row) * K + k0 + ko;
                float4 f0 = *(const float4*)(src);
                float4 f1 = *(const float4*)(src + 4);
                u16x8 p;
                p[0] = f2bf(f0.x); p[1] = f2bf(f0.y); p[2] = f2bf(f0.z); p[3] = f2bf(f0.w);
                p[4] = f2bf(f1.x); p[5] = f2bf(f1.y); p[6] = f2bf(f1.z); p[7] = f2bf(f1.w);
                *(u16x8*)lB = p;
            }
        }
        __syncthreads();

        frag_ab a[4], b[4];
        #pragma unroll
        for (int i = 0; i < 4; ++i)
            a[i] = *(const frag_ab*)&As[(mbase + 16 * i + lrow) * 32 + kq];
        #pragma unroll
        for (int j = 0; j < 4; ++j)
            b[j] = *(const frag_ab*)&Bs[(nbase + 16 * j + lrow) * 32 + kq];
        #pragma unroll
        for (int i = 0; i < 4; ++i)
            #pragma unroll
            for (int j = 0; j < 4; ++j)
                acc[i][j] = __builtin_amdgcn_mfma_f32_16x16x32_bf16(
                    a[i], b[j], acc[i][j], 0, 0, 0);
        __syncthreads();
    }

    const int quad = l >> 4;
    #pragma unroll
    for (int i = 0; i < 4; ++i) {
        #pragma unroll
        for (int j = 0; j < 4; ++j) {
            const int coln = bn + nbase + 16 * j + lrow;
            #pragma unroll
            for (int r = 0; r < 4; ++r) {
                const int rowm = bm + mbase + 16 * i + quad * 4 + r;
                const size_t idx = (size_t)rowm * N + coln;
                float v = acc[i][j][r];
                if (cbf) ((u16*)Cdst)[idx] = f2bf(v);
                else     ((float*)Cdst)[idx] = v;
            }
        }
    }
}

// ---------------------------------------------------------------------------
// Split-bf16 MFMA GEMM: C[m,n] = sum_k A[m,k]*B[n,k] with A,B pre-split into
// (hi,lo) bf16 pairs. acc += ah*bh + al*bh + ah*bl  (al*bl term ~2^-16, dropped)
// -> ~1.5e-5 relative error, i.e. effectively f32-accurate on the matrix pipe.
// 128x128 tile, BK=32, 4 waves, all staging via global_load_lds (16B).
// ---------------------------------------------------------------------------
__global__ __launch_bounds__(256) void gemm_split(
    const u16* __restrict__ Ah, const u16* __restrict__ Al,
    const u16* __restrict__ Bh, const u16* __restrict__ Bl,
    float* __restrict__ Cf,                       // nullable f32 output
    u16* __restrict__ Ch, u16* __restrict__ Cl,   // nullable split output
    const float* __restrict__ D, float alpha, float beta,
    int M, int N, int K)
{
    __shared__ u16 AsH[128 * 32];
    __shared__ u16 AsL[128 * 32];
    __shared__ u16 BsH[128 * 32];
    __shared__ u16 BsL[128 * 32];

    const int bm = blockIdx.y * 128, bn = blockIdx.x * 128;
    const int tid = threadIdx.x;
    const int l = tid & 63, w = tid >> 6;
    const int mbase = (w & 1) * 64, nbase = (w >> 1) * 64;
    const int lrow = l & 15;
    const int kq = (l >> 4) << 3;

    frag_cd acc[4][4];
    #pragma unroll
    for (int i = 0; i < 4; ++i)
        #pragma unroll
        for (int j = 0; j < 4; ++j)
            #pragma unroll
            for (int r = 0; r < 4; ++r) acc[i][j][r] = 0.0f;

    for (int k0 = 0; k0 < K; k0 += 32) {
        #pragma unroll
        for (int half = 0; half < 2; ++half) {
            const int c   = tid + half * 256;
            const int row = c >> 2;
            const int ko  = (c & 3) << 3;
            const size_t ga = (size_t)(bm + row) * K + k0 + ko;
            const size_t gb = (size_t)(bn + row) * K + k0 + ko;
            gl_lds16(Ah + ga, &AsH[c << 3]);
            gl_lds16(Al + ga, &AsL[c << 3]);
            gl_lds16(Bh + gb, &BsH[c << 3]);
            gl_lds16(Bl + gb, &BsL[c << 3]);
        }
        __syncthreads();

        frag_ab ah[4], al4[4], bh[4], bl4[4];
        #pragma unroll
        for (int i = 0; i < 4; ++i) {
            const int ro = (mbase + 16 * i + lrow) * 32 + kq;
            ah[i]  = *(const frag_ab*)&AsH[ro];
            al4[i] = *(const frag_ab*)&AsL[ro];
        }
        #pragma unroll
        for (int j = 0; j < 4; ++j) {
            const int ro = (nbase + 16 * j + lrow) * 32 + kq;
            bh[j]  = *(const frag_ab*)&BsH[ro];
            bl4[j] = *(const frag_ab*)&BsL[ro];
        }
        #pragma unroll
        for (int i = 0; i < 4; ++i)
            #pragma unroll
            for (int j = 0; j < 4; ++j) {
                acc[i][j] = __builtin_amdgcn_mfma_f32_16x16x32_bf16(
                    ah[i], bh[j], acc[i][j], 0, 0, 0);
                acc[i][j] = __builtin_amdgcn_mfma_f32_16x16x32_bf16(
                    al4[i], bh[j], acc[i][j], 0, 0, 0);
                acc[i][j] = __builtin_amdgcn_mfma_f32_16x16x32_bf16(
                    ah[i], bl4[j], acc[i][j], 0, 0, 0);
            }
        __syncthreads();
    }

    const int quad = l >> 4;
    #pragma unroll
    for (int i = 0; i < 4; ++i) {
        #pragma unroll
        for (int j = 0; j < 4; ++j) {
            const int coln = bn + nbase + 16 * j + lrow;
            #pragma unroll
            for (int r = 0; r < 4; ++r) {
                const int rowm = bm + mbase + 16 * i + quad * 4 + r;
                const size_t idx = (size_t)rowm * N + coln;
                float v = beta * acc[i][j][r];
                if (D) v += alpha * D[idx];
                if (Cf) Cf[idx] = v;
                if (Ch) {
                    u16 hi, lo; split2(v, hi, lo);
                    Ch[idx] = hi; Cl[idx] = lo;
                }
            }
        }
    }
}

// ---------------------------------------------------------------------------
// split / transpose-split / recon helpers
// ---------------------------------------------------------------------------
__global__ __launch_bounds__(256) void split_k(const float* __restrict__ X,
                                               u16* __restrict__ H,
                                               u16* __restrict__ L, int n)
{
    int i = blockIdx.x * 256 + threadIdx.x;
    if (i >= n) return;
    u16 hi, lo; split2(X[i], hi, lo);
    H[i] = hi; L[i] = lo;
}

// Th/Tl[n*C_+k] = split(W[k*C_+n])  — LDS 32x32 tile transpose
__global__ __launch_bounds__(256) void transpose_split_k(
    const float* __restrict__ W, u16* __restrict__ Th, u16* __restrict__ Tl)
{
    __shared__ float tile[32][33];
    const int k0 = blockIdx.y * 32;
    const int n0 = blockIdx.x * 32;
    const int tx = threadIdx.x & 31, ty = threadIdx.x >> 5;   // 32 x 8
    #pragma unroll
    for (int r = 0; r < 32; r += 8)
        tile[ty + r][tx] = W[(size_t)(k0 + ty + r) * C_ + n0 + tx];
    __syncthreads();
    #pragma unroll
    for (int r = 0; r < 32; r += 8) {
        float f = tile[tx][ty + r];                 // = W[k0+tx][n0+ty+r]
        size_t idx = (size_t)(n0 + ty + r) * C_ + k0 + tx;
        u16 hi, lo; split2(f, hi, lo);
        Th[idx] = hi; Tl[idx] = lo;
    }
}

// V[i] *= recon(qh,ql)[i]   (prepares A for the proven Y gemm_mfma f32 path)
__global__ __launch_bounds__(256) void qv_k(const u16* __restrict__ qh,
                                            const u16* __restrict__ ql,
                                            float* __restrict__ V, int n)
{
    int i = blockIdx.x * 256 + threadIdx.x;
    if (i >= n) return;
    V[i] = (bf2f(qh[i]) + bf2f(ql[i])) * V[i];
}

// store recon(q) into d_out at element offset, flag-driven dtype
__global__ __launch_bounds__(256) void store_split_k(
    const u16* __restrict__ h, const u16* __restrict__ l,
    void* __restrict__ out, int n, size_t elemoff,
    const int* __restrict__ flag)
{
    int i = blockIdx.x * 256 + threadIdx.x;
    if (i >= n) return;
    float f = bf2f(h[i]) + bf2f(l[i]);
    if (*flag) ((u16*)out)[elemoff + i] = f2bf(f);
    else       ((float*)out)[elemoff + i] = f;
}

// idW[j] = sum_i identf[i] * W[i,j]
__global__ __launch_bounds__(256) void idw_k(
    const float* __restrict__ identf, const float* __restrict__ W,
    float* __restrict__ idW)
{
    int jj = blockIdx.x * 256 + threadIdx.x;   // 0..1023
    float acc = 0.0f;
    for (int i = 0; i < C_; ++i) acc += identf[i] * W[(size_t)i * C_ + jj];
    idW[jj] = acc;
}

// ---------------------------------------------------------------------------
// scan combine: one block (256 threads) per token. Same math as proven
// combine_k; q is carried as (hi,lo) bf16 split pairs (recon err ~2^-17|q|).
// ---------------------------------------------------------------------------
__global__ __launch_bounds__(256) void combine2_k(
    const u16* __restrict__ curh, const u16* __restrict__ curl,
    const float* __restrict__ xW,
    const float* __restrict__ idW, const float* __restrict__ identf,
    u16* __restrict__ nxth, u16* __restrict__ nxtl, int d)
{
    const int token = blockIdx.x;
    const int t = token & (T_ - 1);
    const int j = threadIdx.x;
    const bool hl = (t >= d);
    const size_t rbase = (size_t)token * C_;
    const size_t lbase = hl ? (size_t)(token - d) * C_ : 0;
    const float* leftW  = hl ? xW + lbase : idW;
    const float* rightW = xW + rbase;

    float q[4], k[4], v[4];
    #pragma unroll
    for (int m = 0; m < 4; ++m) {
        const int off = m * HD + j;
        k[m] = bf2f(curh[rbase + off]) + bf2f(curl[rbase + off]);
        if (hl) q[m] = bf2f(curh[lbase + off]) + bf2f(curl[lbase + off]);
        else    q[m] = identf[off];
        v[m] = leftW[off] + rightW[off];
    }

    __shared__ float red[4][16];
    __shared__ float att[16];
    const int lane = j & 63, wid = j >> 6;

    #pragma unroll
    for (int a = 0; a < 4; ++a)
        #pragma unroll
        for (int b = 0; b < 4; ++b) {
            float p = wave_reduce(q[a] * k[b]);
            if (lane == 0) red[wid][a * 4 + b] = p;
        }
    __syncthreads();
    if (j < 16) red[0][j] = (red[0][j] + red[1][j] + red[2][j] + red[3][j]) * 0.0625f;
    __syncthreads();
    if (j < 4) {
        float s0 = red[0][j * 4 + 0], s1 = red[0][j * 4 + 1];
        float s2 = red[0][j * 4 + 2], s3 = red[0][j * 4 + 3];
        float mx = fmaxf(fmaxf(s0, s1), fmaxf(s2, s3));
        float e0 = __expf(s0 - mx), e1 = __expf(s1 - mx);
        float e2 = __expf(s2 - mx), e3 = __expf(s3 - mx);
        float inv = 1.0f / (e0 + e1 + e2 + e3);
        att[j * 4 + 0] = e0 * inv; att[j * 4 + 1] = e1 * inv;
        att[j * 4 + 2] = e2 * inv; att[j * 4 + 3] = e3 * inv;
    }
    __syncthreads();

    float z[4];
    #pragma unroll
    for (int a = 0; a < 4; ++a)
        z[a] = att[a * 4 + 0] * v[0] + att[a * 4 + 1] * v[1]
             + att[a * 4 + 2] * v[2] + att[a * 4 + 3] * v[3];

    #pragma unroll
    for (int a = 0; a < 4; ++a) {
        float p = wave_reduce(z[a] * z[a]);
        if (lane == 0) red[wid][a] = p;
    }
    __syncthreads();
    if (j < 4) {
        float ss = red[0][j] + red[1][j] + red[2][j] + red[3][j];
        att[j] = rsqrtf(ss * (1.0f / HD) + 1e-8f);
    }
    __syncthreads();

    #pragma unroll
    for (int m = 0; m < 4; ++m) {
        const int off = m * HD + j;
        float zn  = z[m] * att[m] * (1.0f / (float)(m + 1));
        float out = q[m] + zn;
        u16 hi, lo; split2(out, hi, lo);
        nxth[rbase + off] = hi;
        nxtl[rbase + off] = lo;
    }
}

// ---------------------------------------------------------------------------
extern "C" void kernel_launch(void* const* d_in, const int* in_sizes, int n_in,
                              void* d_out, int out_size, void* d_ws, size_t ws_size,
                              hipStream_t stream)
{
    const void* x     = d_in[0];
    const void* Wup   = d_in[1];
    const void* Wv    = d_in[2];
    const void* Wproj = d_in[3];
    const void* ident = d_in[4];
    const void* Wraw  = d_in[5];

    float* ws = (float*)d_ws;
    int*   flagp  = (int*)ws;                    // meta[0]
    float* sumsqp = ws + 1;                      // meta[1]
    float* W0     = ws + 256;                    // 1M
    float* W1     = W0 + (1 << 20);              // 1M
    float* G      = W1 + (1 << 20);              // 1M
    float* identf = G + (1 << 20);               // 1024
    float* idW    = identf + 1024;               // 1024
    float* F1     = idW + 1024;                  // 8M f32 scratch (xW / v)
    u16*   WTh    = (u16*)(F1 + (size_t)NTOK * C_);  // W^T split hi (1M u16)
    u16*   WTl    = WTh + (1 << 20);
    u16*   WUh    = WTl + (1 << 20);             // Wup split hi (1M u16)
    u16*   WUl    = WUh + (1 << 20);
    u16*   Q0h    = WUl + (1 << 20);             // q split dbuf A (8M u16 ea)
    u16*   Q0l    = Q0h + (size_t)NTOK * C_;
    u16*   Q1h    = Q0l + (size_t)NTOK * C_;     // q split dbuf B
    u16*   Q1l    = Q1h + (size_t)NTOK * C_;

    const int NC = C_ * C_;          // 1M
    const int NX = NTOK * C_;        // 8M

    // ---- dtype detection ----
    detect_k<<<1, 256, 0, stream>>>((const u16*)Wup, flagp);

    // ---- polar(W_raw) via Newton-Schulz (f32, EXACT round-2 bit path) ----
    hipMemsetAsync(sumsqp, 0, sizeof(float), stream);
    conv_k<<<NC / 256, 256, 0, stream>>>(Wraw, W0, NC, flagp);
    sumsq_k<<<NC / 256, 256, 0, stream>>>(W0, sumsqp);
    scale_k<<<NC / 256, 256, 0, stream>>>(W0, sumsqp);

    float* X = W0; float* Y = W1;
    const dim3 gNS(16, 16);
    for (int it = 0; it < 23; ++it) {           // 18 doubling + 5 polish
        bool polish = (it >= 18);
        float a = polish ? 1.5f : 2.0f;
        float b = polish ? -0.5f : -1.0f;
        gemm_atb_f32<<<gNS, 256, 0, stream>>>(X, X, G, C_, C_, C_);
        gemm_ab_f32<<<gNS, 256, 0, stream>>>(X, G, X, Y, C_, C_, C_, a, b);
        float* tmp = X; X = Y; Y = tmp;
    }
    // X = polar(W_raw)

    conv_k<<<4, 256, 0, stream>>>(ident, identf, 1024, flagp);
    idw_k<<<4, 256, 0, stream>>>(identf, X, idW);

    const dim3 g128(C_ / 128, NTOK / 128);   // (8, 64)

    // ---- q0 = x @ Wup^T  (split-bf16 MFMA, ~f32 accuracy) ----
    conv_k<<<NX / 256, 256, 0, stream>>>(x, F1, NX, flagp);        // x f32
    split_k<<<NX / 256, 256, 0, stream>>>(F1, Q1h, Q1l, NX);       // x split (buf B)
    conv_k<<<NC / 256, 256, 0, stream>>>(Wup, G, NC, flagp);       // Wup f32
    split_k<<<NC / 256, 256, 0, stream>>>(G, WUh, WUl, NC);
    gemm_split<<<g128, 256, 0, stream>>>(Q1h, Q1l, WUh, WUl,
                                         nullptr, Q0h, Q0l,
                                         nullptr, 0.0f, 1.0f, NTOK, C_, C_);

    // ---- W^T split for the scan GEMMs ----
    transpose_split_k<<<dim3(C_ / 32, C_ / 32), 256, 0, stream>>>(X, WTh, WTl);

    // ---- scan: 11 Hillis-Steele steps, q carried as split bf16 pairs ----
    u16 *ch = Q0h, *cl = Q0l, *nh = Q1h, *nl = Q1l;
    for (int d = 1; d < T_; d <<= 1) {
        gemm_split<<<g128, 256, 0, stream>>>(ch, cl, WTh, WTl,
                                             F1, nullptr, nullptr,
                                             nullptr, 0.0f, 1.0f, NTOK, C_, C_);
        combine2_k<<<NTOK, 256, 0, stream>>>(ch, cl, F1, idW, identf, nh, nl, d);
        u16* t1 = ch; ch = nh; nh = t1;
        u16* t2 = cl; cl = nl; nl = t2;
    }
    // 11 steps (odd) -> ch/cl = Q1h/Q1l hold q

    // ---- v = x @ Wv^T  (MFMA, proven output-0 path) -> F1 ----
    gemm_mfma<<<g128, 256, 0, stream>>>(x, nullptr, 2, Wv, 2, F1, 0,
                                        flagp, NTOK, C_, C_);

    // ---- F1 = q .* v ; Y = F1 @ Wproj^T -> d_out[0:NX]  (proven MFMA) ----
    qv_k<<<NX / 256, 256, 0, stream>>>(ch, cl, F1, NX);
    gemm_mfma<<<g128, 256, 0, stream>>>(F1, nullptr, 0, Wproj, 2, d_out, 1,
                                        flagp, NTOK, C_, C_);

    // ---- second output: q ----
    store_split_k<<<NX / 256, 256, 0, stream>>>(ch, cl, d_out, NX, (size_t)NX, flagp);
}

// Round 3
// 2505.600 us; speedup vs baseline: 2.4433x; 1.7299x over previous
//
#include <hip/hip_runtime.h>
#include <hip/hip_bf16.h>

#define DEVINL __device__ __forceinline__

constexpr int B_   = 4;
constexpr int T_   = 2048;
constexpr int C_   = 1024;
constexpr int NTOK = B_ * T_;      // 8192
constexpr int HD   = 256;          // C_/4

typedef unsigned short u16;
typedef __attribute__((ext_vector_type(8))) short  frag_ab;  // 8 bf16 (4 VGPRs)
typedef __attribute__((ext_vector_type(4))) float  frag_cd;  // 4 fp32
typedef __attribute__((ext_vector_type(8))) u16    u16x8;
typedef __attribute__((ext_vector_type(4))) u16    u16x4;

DEVINL float bf2f(u16 u) {
    unsigned int x = ((unsigned int)u) << 16;
    return __uint_as_float(x);
}
DEVINL u16 f2bf(float f) {
    unsigned int x = __float_as_uint(f);
    unsigned int r = (x + 0x7fffu + ((x >> 16) & 1u)) >> 16;
    return (u16)r;
}
// f == bf2f(h) + bf2f(l) + O(2^-18 |f|); residual subtraction exact (Sterbenz).
DEVINL void split2(float f, u16& h, u16& l) {
    h = f2bf(f);
    l = f2bf(f - bf2f(h));
}
DEVINL float wave_reduce(float v) {
    #pragma unroll
    for (int off = 32; off > 0; off >>= 1) v += __shfl_down(v, off, 64);
    return v;
}
DEVINL void gl_lds16(const void* g, void* l) {
    __builtin_amdgcn_global_load_lds(
        (const __attribute__((address_space(1))) unsigned int*)g,
        (__attribute__((address_space(3))) unsigned int*)l, 16, 0, 0);
}

// XCD-aware remap for (8,64) grids: hw%8 = XCD (round-robin); give each XCD
// 8 M-panels x 8 N-cols so its A footprint (4MB split / 2MB bf16) is L2-resident
// and each A panel is fetched by exactly one XCD (was 8x over-fetch).
DEVINL void swizzle_block(int& bx, int& by) {
    const int hw = (int)(blockIdx.x + gridDim.x * blockIdx.y);
    if (gridDim.x == 8 && gridDim.y == 64) {
        const int xcd = hw & 7, idx = hw >> 3;
        by = xcd * 8 + (idx & 7);
        bx = idx >> 3;
    } else { bx = blockIdx.x; by = blockIdx.y; }
}

// ---------------------------------------------------------------------------
// dtype auto-detect (flag: 1 = bf16 inputs, 0 = f32 inputs)
// ---------------------------------------------------------------------------
__global__ __launch_bounds__(256) void detect_k(const u16* __restrict__ w,
                                                int* __restrict__ flag)
{
    int tid = threadIdx.x;
    int cnt = 0;
    for (int i = tid; i < 4096; i += 256) {
        u16 u = w[2 * i];
        int e = (u >> 7) & 0xFF;
        if (u == 0 || (e >= 96 && e <= 134)) cnt++;
    }
    __shared__ int sh[256];
    sh[tid] = cnt; __syncthreads();
    for (int s = 128; s > 0; s >>= 1) {
        if (tid < s) sh[tid] += sh[tid + s];
        __syncthreads();
    }
    if (tid == 0) *flag = (sh[0] > 2048) ? 1 : 0;
}

__global__ __launch_bounds__(256) void conv_k(const void* __restrict__ src,
                                              float* __restrict__ dst, int n,
                                              const int* __restrict__ flag)
{
    int i = blockIdx.x * 256 + threadIdx.x;
    if (i >= n) return;
    if (*flag) dst[i] = bf2f(((const u16*)src)[i]);
    else       dst[i] = ((const float*)src)[i];
}

// src(flag dtype) -> split hi/lo, 4 elems/thread
__global__ __launch_bounds__(256) void conv_split_k(const void* __restrict__ src,
                                                    u16* __restrict__ H,
                                                    u16* __restrict__ L, int n4,
                                                    const int* __restrict__ flag)
{
    int i = blockIdx.x * 256 + threadIdx.x;
    if (i >= n4) return;
    float f[4];
    if (*flag) {
        u16x4 u = ((const u16x4*)src)[i];
        f[0] = bf2f(u[0]); f[1] = bf2f(u[1]); f[2] = bf2f(u[2]); f[3] = bf2f(u[3]);
    } else {
        float4 v = ((const float4*)src)[i];
        f[0] = v.x; f[1] = v.y; f[2] = v.z; f[3] = v.w;
    }
    u16x4 h, lo;
    #pragma unroll
    for (int r = 0; r < 4; ++r) { u16 a, b; split2(f[r], a, b); h[r] = a; lo[r] = b; }
    ((u16x4*)H)[i] = h; ((u16x4*)L)[i] = lo;
}

// src(flag dtype) -> plain bf16, 4 elems/thread
__global__ __launch_bounds__(256) void convb_k(const void* __restrict__ src,
                                               u16* __restrict__ out, int n4,
                                               const int* __restrict__ flag)
{
    int i = blockIdx.x * 256 + threadIdx.x;
    if (i >= n4) return;
    u16x4 o;
    if (*flag) {
        o = ((const u16x4*)src)[i];
    } else {
        float4 v = ((const float4*)src)[i];
        o[0] = f2bf(v.x); o[1] = f2bf(v.y); o[2] = f2bf(v.z); o[3] = f2bf(v.w);
    }
    ((u16x4*)out)[i] = o;
}

__global__ __launch_bounds__(256) void sumsq_k(const float* __restrict__ X,
                                               float* __restrict__ sumsq)
{
    int i = blockIdx.x * 256 + threadIdx.x;
    float f = X[i];
    float p = wave_reduce(f * f);
    __shared__ float r[4];
    int lane = threadIdx.x & 63, w = threadIdx.x >> 6;
    if (lane == 0) r[w] = p;
    __syncthreads();
    if (threadIdx.x == 0) atomicAdd(sumsq, r[0] + r[1] + r[2] + r[3]);
}

__global__ __launch_bounds__(256) void scale_k(float* __restrict__ X,
                                               const float* __restrict__ sumsq)
{
    int i = blockIdx.x * 256 + threadIdx.x;
    float F = sqrtf(*sumsq);
    float s = 16.0f / (1.1f * F);   // Gaussian: sigma_max ~= F/16; 10% margin
    X[i] *= s;
}

// plain f32 -> split (scalar, small arrays)
__global__ __launch_bounds__(256) void split_k(const float* __restrict__ X,
                                               u16* __restrict__ H,
                                               u16* __restrict__ L, int n)
{
    int i = blockIdx.x * 256 + threadIdx.x;
    if (i >= n) return;
    u16 hi, lo; split2(X[i], hi, lo);
    H[i] = hi; L[i] = lo;
}

// Th/Tl[n*C_+k] = split(W[k*C_+n])  — LDS 32x32 tile transpose
__global__ __launch_bounds__(256) void transpose_split_k(
    const float* __restrict__ W, u16* __restrict__ Th, u16* __restrict__ Tl)
{
    __shared__ float tile[32][33];
    const int k0 = blockIdx.y * 32;
    const int n0 = blockIdx.x * 32;
    const int tx = threadIdx.x & 31, ty = threadIdx.x >> 5;   // 32 x 8
    #pragma unroll
    for (int r = 0; r < 32; r += 8)
        tile[ty + r][tx] = W[(size_t)(k0 + ty + r) * C_ + n0 + tx];
    __syncthreads();
    #pragma unroll
    for (int r = 0; r < 32; r += 8) {
        float f = tile[tx][ty + r];                 // = W[k0+tx][n0+ty+r]
        size_t idx = (size_t)(n0 + ty + r) * C_ + k0 + tx;
        u16 hi, lo; split2(f, hi, lo);
        Th[idx] = hi; Tl[idx] = lo;
    }
}

// ---------------------------------------------------------------------------
// NS split-bf16 MFMA GEMM: C[m,n] = beta*sum_k A[m,k]*B[n,k] + alpha*D[m,n]
// 64x64 tile, BK=64 ([2][64][32] panel layout keeps 64B row stride), 4-term
// (hh+lh+hl+ll -> ~2^-17 rel err), double-buffered 2-phase prefetch.
// ---------------------------------------------------------------------------
__global__ __launch_bounds__(256) void gemm_split64(
    const u16* __restrict__ Ah, const u16* __restrict__ Al,
    const u16* __restrict__ Bh, const u16* __restrict__ Bl,
    float* __restrict__ Cf, u16* __restrict__ Ch, u16* __restrict__ Cl,
    const float* __restrict__ D, float alpha, float beta,
    int M, int N, int K)
{
    __shared__ u16 sAh[2][2][64][32];   // [dbuf][ks][row][k]  16 KB
    __shared__ u16 sAl[2][2][64][32];
    __shared__ u16 sBh[2][2][64][32];
    __shared__ u16 sBl[2][2][64][32];   // total 64 KB

    const int bm = blockIdx.y * 64, bn = blockIdx.x * 64;
    const int tid = threadIdx.x;
    const int l = tid & 63, w = tid >> 6;
    const int mbase = (w & 1) * 32, nbase = (w >> 1) * 32;
    const int lrow = l & 15, kq = (l >> 4) << 3;

    frag_cd acc[2][2];
    #pragma unroll
    for (int i = 0; i < 2; ++i)
        #pragma unroll
        for (int j = 0; j < 2; ++j)
            #pragma unroll
            for (int r = 0; r < 4; ++r) acc[i][j][r] = 0.0f;

    // per array: 64x64 u16 = 512 16B-chunks; c = tid + 256*half
    // c = ks*256 + row*4 + q  -> LDS linear offset c*8 (lane-linear for gl_lds)
    auto STAGE = [&](int buf, int k0) {
        #pragma unroll
        for (int half = 0; half < 2; ++half) {
            const int c   = tid + half * 256;
            const int row = (c >> 2) & 63;
            const int ko  = half * 32 + (c & 3) * 8;
            const size_t ga = (size_t)(bm + row) * K + k0 + ko;
            const size_t gb = (size_t)(bn + row) * K + k0 + ko;
            gl_lds16(Ah + ga, &sAh[buf][0][0][0] + (c << 3));
            gl_lds16(Al + ga, &sAl[buf][0][0][0] + (c << 3));
            gl_lds16(Bh + gb, &sBh[buf][0][0][0] + (c << 3));
            gl_lds16(Bl + gb, &sBl[buf][0][0][0] + (c << 3));
        }
    };

    STAGE(0, 0);
    __syncthreads();
    const int NT = K >> 6;
    int cur = 0;
    for (int t = 0; t < NT; ++t) {
        if (t + 1 < NT) STAGE(cur ^ 1, (t + 1) << 6);
        #pragma unroll
        for (int ks = 0; ks < 2; ++ks) {
            frag_ab ah[2], al2[2], bh[2], bl2[2];
            #pragma unroll
            for (int i = 0; i < 2; ++i) {
                const int ro = mbase + 16 * i + lrow;
                ah[i]  = *(const frag_ab*)&sAh[cur][ks][ro][kq];
                al2[i] = *(const frag_ab*)&sAl[cur][ks][ro][kq];
            }
            #pragma unroll
            for (int j = 0; j < 2; ++j) {
                const int ro = nbase + 16 * j + lrow;
                bh[j]  = *(const frag_ab*)&sBh[cur][ks][ro][kq];
                bl2[j] = *(const frag_ab*)&sBl[cur][ks][ro][kq];
            }
            #pragma unroll
            for (int i = 0; i < 2; ++i)
                #pragma unroll
                for (int j = 0; j < 2; ++j) {
                    acc[i][j] = __builtin_amdgcn_mfma_f32_16x16x32_bf16(
                        ah[i], bh[j], acc[i][j], 0, 0, 0);
                    acc[i][j] = __builtin_amdgcn_mfma_f32_16x16x32_bf16(
                        al2[i], bh[j], acc[i][j], 0, 0, 0);
                    acc[i][j] = __builtin_amdgcn_mfma_f32_16x16x32_bf16(
                        ah[i], bl2[j], acc[i][j], 0, 0, 0);
                    acc[i][j] = __builtin_amdgcn_mfma_f32_16x16x32_bf16(
                        al2[i], bl2[j], acc[i][j], 0, 0, 0);
                }
        }
        __syncthreads();
        cur ^= 1;
    }

    const int quad = l >> 4;
    #pragma unroll
    for (int i = 0; i < 2; ++i) {
        #pragma unroll
        for (int j = 0; j < 2; ++j) {
            const int coln = bn + nbase + 16 * j + lrow;
            #pragma unroll
            for (int r = 0; r < 4; ++r) {
                const int rowm = bm + mbase + 16 * i + quad * 4 + r;
                const size_t idx = (size_t)rowm * N + coln;
                float v = beta * acc[i][j][r];
                if (D) v += alpha * D[idx];
                if (Cf) Cf[idx] = v;
                if (Ch) { u16 hi, lo; split2(v, hi, lo); Ch[idx] = hi; Cl[idx] = lo; }
            }
        }
    }
}

// ---------------------------------------------------------------------------
// Scan split-bf16 MFMA GEMM: C[m,n] = sum_k A[m,k]*B[n,k], 3-term (bit-identical
// arithmetic to round-1 gemm_split). 128x128 tile, BK=32, double-buffered
// 2-phase prefetch (one barrier/k-step), XCD-swizzled blocks.
// ---------------------------------------------------------------------------
__global__ __launch_bounds__(256) void gemm_split(
    const u16* __restrict__ Ah, const u16* __restrict__ Al,
    const u16* __restrict__ Bh, const u16* __restrict__ Bl,
    float* __restrict__ Cf, u16* __restrict__ Ch, u16* __restrict__ Cl,
    int M, int N, int K)
{
    __shared__ u16 sAh[2][128][32];   // 16 KB each, 64 KB total
    __shared__ u16 sAl[2][128][32];
    __shared__ u16 sBh[2][128][32];
    __shared__ u16 sBl[2][128][32];

    int bx, by; swizzle_block(bx, by);
    const int bm = by * 128, bn = bx * 128;
    const int tid = threadIdx.x;
    const int l = tid & 63, w = tid >> 6;
    const int mbase = (w & 1) * 64, nbase = (w >> 1) * 64;
    const int lrow = l & 15, kq = (l >> 4) << 3;

    frag_cd acc[4][4];
    #pragma unroll
    for (int i = 0; i < 4; ++i)
        #pragma unroll
        for (int j = 0; j < 4; ++j)
            #pragma unroll
            for (int r = 0; r < 4; ++r) acc[i][j][r] = 0.0f;

    auto STAGE = [&](int buf, int k0) {
        #pragma unroll
        for (int half = 0; half < 2; ++half) {
            const int c   = tid + half * 256;
            const int row = c >> 2;
            const int ko  = (c & 3) << 3;
            const size_t ga = (size_t)(bm + row) * K + k0 + ko;
            const size_t gb = (size_t)(bn + row) * K + k0 + ko;
            gl_lds16(Ah + ga, &sAh[buf][0][0] + (c << 3));
            gl_lds16(Al + ga, &sAl[buf][0][0] + (c << 3));
            gl_lds16(Bh + gb, &sBh[buf][0][0] + (c << 3));
            gl_lds16(Bl + gb, &sBl[buf][0][0] + (c << 3));
        }
    };

    STAGE(0, 0);
    __syncthreads();
    const int NT = K >> 5;
    int cur = 0;
    for (int t = 0; t < NT; ++t) {
        if (t + 1 < NT) STAGE(cur ^ 1, (t + 1) << 5);
        frag_ab ah[4], al4[4], bh[4], bl4[4];
        #pragma unroll
        for (int i = 0; i < 4; ++i) {
            const int ro = mbase + 16 * i + lrow;
            ah[i]  = *(const frag_ab*)&sAh[cur][ro][kq];
            al4[i] = *(const frag_ab*)&sAl[cur][ro][kq];
        }
        #pragma unroll
        for (int j = 0; j < 4; ++j) {
            const int ro = nbase + 16 * j + lrow;
            bh[j]  = *(const frag_ab*)&sBh[cur][ro][kq];
            bl4[j] = *(const frag_ab*)&sBl[cur][ro][kq];
        }
        #pragma unroll
        for (int i = 0; i < 4; ++i)
            #pragma unroll
            for (int j = 0; j < 4; ++j) {
                acc[i][j] = __builtin_amdgcn_mfma_f32_16x16x32_bf16(
                    ah[i], bh[j], acc[i][j], 0, 0, 0);
                acc[i][j] = __builtin_amdgcn_mfma_f32_16x16x32_bf16(
                    al4[i], bh[j], acc[i][j], 0, 0, 0);
                acc[i][j] = __builtin_amdgcn_mfma_f32_16x16x32_bf16(
                    ah[i], bl4[j], acc[i][j], 0, 0, 0);
            }
        __syncthreads();
        cur ^= 1;
    }

    const int quad = l >> 4;
    #pragma unroll
    for (int i = 0; i < 4; ++i) {
        #pragma unroll
        for (int j = 0; j < 4; ++j) {
            const int coln = bn + nbase + 16 * j + lrow;
            #pragma unroll
            for (int r = 0; r < 4; ++r) {
                const int rowm = bm + mbase + 16 * i + quad * 4 + r;
                const size_t idx = (size_t)rowm * N + coln;
                float v = acc[i][j][r];
                if (Cf) Cf[idx] = v;
                if (Ch) { u16 hi, lo; split2(v, hi, lo); Ch[idx] = hi; Cl[idx] = lo; }
            }
        }
    }
}

// ---------------------------------------------------------------------------
// Plain bf16 MFMA GEMM (v, Y): C[m,n] = sum_k A[m,k]*B[n,k], A/B pre-converted
// u16 bf16 (pure global_load_lds staging). 128x128, BK=64 panel layout,
// double-buffered 2-phase, XCD swizzle. Accumulation order identical to the
// proven round-1 gemm_mfma (ascending k, 32 per MFMA).
// ---------------------------------------------------------------------------
__global__ __launch_bounds__(256) void gemm_bf16(
    const u16* __restrict__ Ab, const u16* __restrict__ Bb,
    void* __restrict__ Cdst, int cmode, const int* __restrict__ flag,
    int M, int N, int K)
{
    __shared__ u16 As[2][2][128][32];   // [dbuf][ks][row][k]  32 KB
    __shared__ u16 Bs[2][2][128][32];   // 64 KB total
    const int cbf = (cmode == 1) ? *flag : 0;

    int bx, by; swizzle_block(bx, by);
    const int bm = by * 128, bn = bx * 128;
    const int tid = threadIdx.x;
    const int l = tid & 63, w = tid >> 6;
    const int mbase = (w & 1) * 64, nbase = (w >> 1) * 64;
    const int lrow = l & 15, kq = (l >> 4) << 3;

    frag_cd acc[4][4];
    #pragma unroll
    for (int i = 0; i < 4; ++i)
        #pragma unroll
        for (int j = 0; j < 4; ++j)
            #pragma unroll
            for (int r = 0; r < 4; ++r) acc[i][j][r] = 0.0f;

    // per array: 128x64 u16 = 1024 16B-chunks; c = tid + 256*half (4 halves)
    // c = ks*512 + row*4 + q -> LDS linear c*8
    auto STAGE = [&](int buf, int k0) {
        #pragma unroll
        for (int half = 0; half < 4; ++half) {
            const int c   = tid + half * 256;
            const int ks  = c >> 9;
            const int row = (c >> 2) & 127;
            const int ko  = ks * 32 + (c & 3) * 8;
            const size_t ga = (size_t)(bm + row) * K + k0 + ko;
            const size_t gb = (size_t)(bn + row) * K + k0 + ko;
            gl_lds16(Ab + ga, &As[buf][0][0][0] + (c << 3));
            gl_lds16(Bb + gb, &Bs[buf][0][0][0] + (c << 3));
        }
    };

    STAGE(0, 0);
    __syncthreads();
    const int NT = K >> 6;
    int cur = 0;
    for (int t = 0; t < NT; ++t) {
        if (t + 1 < NT) STAGE(cur ^ 1, (t + 1) << 6);
        #pragma unroll
        for (int ks = 0; ks < 2; ++ks) {
            frag_ab a[4], b[4];
            #pragma unroll
            for (int i = 0; i < 4; ++i)
                a[i] = *(const frag_ab*)&As[cur][ks][mbase + 16 * i + lrow][kq];
            #pragma unroll
            for (int j = 0; j < 4; ++j)
                b[j] = *(const frag_ab*)&Bs[cur][ks][nbase + 16 * j + lrow][kq];
            #pragma unroll
            for (int i = 0; i < 4; ++i)
                #pragma unroll
                for (int j = 0; j < 4; ++j)
                    acc[i][j] = __builtin_amdgcn_mfma_f32_16x16x32_bf16(
                        a[i], b[j], acc[i][j], 0, 0, 0);
        }
        __syncthreads();
        cur ^= 1;
    }

    const int quad = l >> 4;
    #pragma unroll
    for (int i = 0; i < 4; ++i) {
        #pragma unroll
        for (int j = 0; j < 4; ++j) {
            const int coln = bn + nbase + 16 * j + lrow;
            #pragma unroll
            for (int r = 0; r < 4; ++r) {
                const int rowm = bm + mbase + 16 * i + quad * 4 + r;
                const size_t idx = (size_t)rowm * N + coln;
                float v = acc[i][j][r];
                if (cbf) ((u16*)Cdst)[idx] = f2bf(v);
                else     ((float*)Cdst)[idx] = v;
            }
        }
    }
}

// ---------------------------------------------------------------------------
// qv = bf16(recon(qh,ql) * v) — A operand for the Y GEMM
// ---------------------------------------------------------------------------
__global__ __launch_bounds__(256) void qvb_k(const u16* __restrict__ qh,
                                             const u16* __restrict__ ql,
                                             const float* __restrict__ V,
                                             u16* __restrict__ out, int n4)
{
    int i = blockIdx.x * 256 + threadIdx.x;
    if (i >= n4) return;
    u16x4 h = ((const u16x4*)qh)[i], lo = ((const u16x4*)ql)[i];
    float4 v = ((const float4*)V)[i];
    u16x4 o;
    o[0] = f2bf((bf2f(h[0]) + bf2f(lo[0])) * v.x);
    o[1] = f2bf((bf2f(h[1]) + bf2f(lo[1])) * v.y);
    o[2] = f2bf((bf2f(h[2]) + bf2f(lo[2])) * v.z);
    o[3] = f2bf((bf2f(h[3]) + bf2f(lo[3])) * v.w);
    ((u16x4*)out)[i] = o;
}

// store recon(q) into d_out at element offset (in float4/u16x4 units)
__global__ __launch_bounds__(256) void store_split_k(
    const u16* __restrict__ h, const u16* __restrict__ l,
    void* __restrict__ out, int n4, size_t off4,
    const int* __restrict__ flag)
{
    int i = blockIdx.x * 256 + threadIdx.x;
    if (i >= n4) return;
    u16x4 hh = ((const u16x4*)h)[i], ll = ((const u16x4*)l)[i];
    float4 f;
    f.x = bf2f(hh[0]) + bf2f(ll[0]);
    f.y = bf2f(hh[1]) + bf2f(ll[1]);
    f.z = bf2f(hh[2]) + bf2f(ll[2]);
    f.w = bf2f(hh[3]) + bf2f(ll[3]);
    if (*flag) {
        u16x4 o; o[0] = f2bf(f.x); o[1] = f2bf(f.y); o[2] = f2bf(f.z); o[3] = f2bf(f.w);
        ((u16x4*)out)[off4 + i] = o;
    } else {
        ((float4*)out)[off4 + i] = f;
    }
}

// idW[j] = sum_i identf[i] * W[i,j] — 64 blocks x 16 rows, atomic combine
__global__ __launch_bounds__(256) void idw2_k(
    const float* __restrict__ identf, const float* __restrict__ W,
    float* __restrict__ idW)
{
    const int b = blockIdx.x;
    const int j = threadIdx.x;
    float a0 = 0, a1 = 0, a2 = 0, a3 = 0;
    #pragma unroll
    for (int ii = 0; ii < 16; ++ii) {
        const int i = b * 16 + ii;
        const float s = identf[i];
        const float* row = W + (size_t)i * C_;
        a0 += s * row[j];
        a1 += s * row[j + 256];
        a2 += s * row[j + 512];
        a3 += s * row[j + 768];
    }
    atomicAdd(idW + j, a0);       atomicAdd(idW + j + 256, a1);
    atomicAdd(idW + j + 512, a2); atomicAdd(idW + j + 768, a3);
}

// ---------------------------------------------------------------------------
// scan combine: one block (256 threads) per token. UNCHANGED from round 1.
// ---------------------------------------------------------------------------
__global__ __launch_bounds__(256) void combine2_k(
    const u16* __restrict__ curh, const u16* __restrict__ curl,
    const float* __restrict__ xW,
    const float* __restrict__ idW, const float* __restrict__ identf,
    u16* __restrict__ nxth, u16* __restrict__ nxtl, int d)
{
    const int token = blockIdx.x;
    const int t = token & (T_ - 1);
    const int j = threadIdx.x;
    const bool hl = (t >= d);
    const size_t rbase = (size_t)token * C_;
    const size_t lbase = hl ? (size_t)(token - d) * C_ : 0;
    const float* leftW  = hl ? xW + lbase : idW;
    const float* rightW = xW + rbase;

    float q[4], k[4], v[4];
    #pragma unroll
    for (int m = 0; m < 4; ++m) {
        const int off = m * HD + j;
        k[m] = bf2f(curh[rbase + off]) + bf2f(curl[rbase + off]);
        if (hl) q[m] = bf2f(curh[lbase + off]) + bf2f(curl[lbase + off]);
        else    q[m] = identf[off];
        v[m] = leftW[off] + rightW[off];
    }

    __shared__ float red[4][16];
    __shared__ float att[16];
    const int lane = j & 63, wid = j >> 6;

    #pragma unroll
    for (int a = 0; a < 4; ++a)
        #pragma unroll
        for (int b = 0; b < 4; ++b) {
            float p = wave_reduce(q[a] * k[b]);
            if (lane == 0) red[wid][a * 4 + b] = p;
        }
    __syncthreads();
    if (j < 16) red[0][j] = (red[0][j] + red[1][j] + red[2][j] + red[3][j]) * 0.0625f;
    __syncthreads();
    if (j < 4) {
        float s0 = red[0][j * 4 + 0], s1 = red[0][j * 4 + 1];
        float s2 = red[0][j * 4 + 2], s3 = red[0][j * 4 + 3];
        float mx = fmaxf(fmaxf(s0, s1), fmaxf(s2, s3));
        float e0 = __expf(s0 - mx), e1 = __expf(s1 - mx);
        float e2 = __expf(s2 - mx), e3 = __expf(s3 - mx);
        float inv = 1.0f / (e0 + e1 + e2 + e3);
        att[j * 4 + 0] = e0 * inv; att[j * 4 + 1] = e1 * inv;
        att[j * 4 + 2] = e2 * inv; att[j * 4 + 3] = e3 * inv;
    }
    __syncthreads();

    float z[4];
    #pragma unroll
    for (int a = 0; a < 4; ++a)
        z[a] = att[a * 4 + 0] * v[0] + att[a * 4 + 1] * v[1]
             + att[a * 4 + 2] * v[2] + att[a * 4 + 3] * v[3];

    #pragma unroll
    for (int a = 0; a < 4; ++a) {
        float p = wave_reduce(z[a] * z[a]);
        if (lane == 0) red[wid][a] = p;
    }
    __syncthreads();
    if (j < 4) {
        float ss = red[0][j] + red[1][j] + red[2][j] + red[3][j];
        att[j] = rsqrtf(ss * (1.0f / HD) + 1e-8f);
    }
    __syncthreads();

    #pragma unroll
    for (int m = 0; m < 4; ++m) {
        const int off = m * HD + j;
        float zn  = z[m] * att[m] * (1.0f / (float)(m + 1));
        float out = q[m] + zn;
        u16 hi, lo; split2(out, hi, lo);
        nxth[rbase + off] = hi;
        nxtl[rbase + off] = lo;
    }
}

// ---------------------------------------------------------------------------
extern "C" void kernel_launch(void* const* d_in, const int* in_sizes, int n_in,
                              void* d_out, int out_size, void* d_ws, size_t ws_size,
                              hipStream_t stream)
{
    const void* x     = d_in[0];
    const void* Wup   = d_in[1];
    const void* Wv    = d_in[2];
    const void* Wproj = d_in[3];
    const void* ident = d_in[4];
    const void* Wraw  = d_in[5];

    float* ws = (float*)d_ws;
    int*   flagp  = (int*)ws;                    // meta[0]
    float* sumsqp = ws + 1;                      // meta[1]
    float* W0     = ws + 256;                    // 1M f32
    float* W1     = W0 + (1 << 20);              // 1M f32
    float* identf = W1 + (1 << 20);              // 1024
    float* idW    = identf + 1024;               // 1024
    float* F1     = idW + 1024;                  // 8M f32 (xW / v scratch)
    u16*   WTh    = (u16*)(F1 + (size_t)NTOK * C_);  // W^T split hi (1M u16)
    u16*   WTl    = WTh + (1 << 20);
    u16*   WUh    = WTl + (1 << 20);             // Wup split / G split / WVb
    u16*   WUl    = WUh + (1 << 20);             //            …        / WPb
    u16*   Q0h    = WUl + (1 << 20);             // q split dbuf A (8M u16 ea)
    u16*   Q0l    = Q0h + (size_t)NTOK * C_;
    u16*   Q1h    = Q0l + (size_t)NTOK * C_;     // q split dbuf B
    u16*   Q1l    = Q1h + (size_t)NTOK * C_;

    const int NC = C_ * C_;          // 1M
    const int NX = NTOK * C_;        // 8M

    // ---- dtype detection ----
    detect_k<<<1, 256, 0, stream>>>((const u16*)Wup, flagp);

    // ---- polar(W_raw) via Newton-Schulz, split-bf16 MFMA (4-term) ----
    hipMemsetAsync(sumsqp, 0, sizeof(float), stream);
    conv_k<<<NC / 256, 256, 0, stream>>>(Wraw, W0, NC, flagp);
    sumsq_k<<<NC / 256, 256, 0, stream>>>(W0, sumsqp);
    scale_k<<<NC / 256, 256, 0, stream>>>(W0, sumsqp);

    // NS split scratch aliases (Q0 region is dead until q0; WU* dead until q0)
    u16* Gh   = WUh;  u16* Gl = WUl;
    u16* Xh2[2] = { Q0h,                 Q0h + 2 * (1 << 20) };
    u16* Xl2[2] = { Q0h + (1 << 20),     Q0h + 3 * (1 << 20) };

    split_k<<<NC / 256, 256, 0, stream>>>(W0, Xh2[0], Xl2[0], NC);
    transpose_split_k<<<dim3(32, 32), 256, 0, stream>>>(W0, WTh, WTl);

    float* Xf = W0; float* Yf = W1; int cur = 0;
    const dim3 gNS(16, 16);
    for (int it = 0; it < 23; ++it) {           // 18 doubling + 5 polish
        bool polish = (it >= 18);
        float a = polish ? 1.5f : 2.0f;
        float b = polish ? -0.5f : -1.0f;
        // G = X^T X  (A = B = X^T split) -> split output
        gemm_split64<<<gNS, 256, 0, stream>>>(WTh, WTl, WTh, WTl,
                                              nullptr, Gh, Gl,
                                              nullptr, 0.0f, 1.0f, C_, C_, C_);
        // Y = b*(X G) + a*X  (G symmetric) -> f32 + next-iter row-major split
        gemm_split64<<<gNS, 256, 0, stream>>>(Xh2[cur], Xl2[cur], Gh, Gl,
                                              Yf, Xh2[cur ^ 1], Xl2[cur ^ 1],
                                              Xf, a, b, C_, C_, C_);
        // transposed split of Y for next iteration (last one = scan's W^T)
        transpose_split_k<<<dim3(32, 32), 256, 0, stream>>>(Yf, WTh, WTl);
        float* tmp = Xf; Xf = Yf; Yf = tmp; cur ^= 1;
    }
    // Xf = polar(W_raw) f32 ; WTh/WTl = W^T split, ready for the scan

    conv_k<<<4, 256, 0, stream>>>(ident, identf, 1024, flagp);
    hipMemsetAsync(idW, 0, C_ * sizeof(float), stream);
    idw2_k<<<64, 256, 0, stream>>>(identf, Xf, idW);

    const dim3 g128(C_ / 128, NTOK / 128);   // (8, 64)

    // ---- q0 = x @ Wup^T  (split-bf16 MFMA, bit-identical math to round 1) ----
    conv_split_k<<<NX / 1024, 256, 0, stream>>>(x, Q1h, Q1l, NX / 4, flagp);
    conv_split_k<<<NC / 1024, 256, 0, stream>>>(Wup, WUh, WUl, NC / 4, flagp);
    gemm_split<<<g128, 256, 0, stream>>>(Q1h, Q1l, WUh, WUl,
                                         nullptr, Q0h, Q0l, NTOK, C_, C_);

    // ---- scan: 11 Hillis-Steele steps, q carried as split bf16 pairs ----
    u16 *ch = Q0h, *cl = Q0l, *nh = Q1h, *nl = Q1l;
    for (int d = 1; d < T_; d <<= 1) {
        gemm_split<<<g128, 256, 0, stream>>>(ch, cl, WTh, WTl,
                                             F1, nullptr, nullptr, NTOK, C_, C_);
        combine2_k<<<NTOK, 256, 0, stream>>>(ch, cl, F1, idW, identf, nh, nl, d);
        u16* t1 = ch; ch = nh; nh = t1;
        u16* t2 = cl; cl = nl; nl = t2;
    }
    // 11 steps (odd) -> ch/cl = Q1h/Q1l hold q; Q0*, F1, WU* free

    // ---- pre-convert weights / x to bf16 (values identical to round-1 staging) ----
    convb_k<<<NC / 1024, 256, 0, stream>>>(Wv,    WUh, NC / 4, flagp);   // WVb
    convb_k<<<NC / 1024, 256, 0, stream>>>(Wproj, WUl, NC / 4, flagp);   // WPb
    convb_k<<<NX / 1024, 256, 0, stream>>>(x,     Q0h, NX / 4, flagp);   // xb

    // ---- v = x @ Wv^T  (pure bf16 MFMA) -> F1 f32 ----
    gemm_bf16<<<g128, 256, 0, stream>>>(Q0h, WUh, F1, 0, flagp, NTOK, C_, C_);

    // ---- Y = (q .* v) @ Wproj^T -> d_out[0:NX] ----
    qvb_k<<<NX / 1024, 256, 0, stream>>>(ch, cl, F1, Q0l, NX / 4);
    gemm_bf16<<<g128, 256, 0, stream>>>(Q0l, WUl, d_out, 1, flagp, NTOK, C_, C_);

    // ---- second output: q ----
    store_split_k<<<NX / 1024, 256, 0, stream>>>(ch, cl, d_out, NX / 4,
                                                 (size_t)(NX / 4), flagp);
}